// Round 17
// baseline (436.472 us; speedup 1.0000x reference)
//
#include <hip/hip_runtime.h>

typedef float vf4 __attribute__((ext_vector_type(4)));
typedef int vi4 __attribute__((ext_vector_type(4)));
typedef int vi2 __attribute__((ext_vector_type(2)));
typedef short short8 __attribute__((ext_vector_type(8)));
typedef unsigned short ushort8 __attribute__((ext_vector_type(8)));

#define LL 1024
#define OO 128
#define BBATCH 4096
#define NS 511          // sites per sweep
#define NP 256          // pair steps (255 real pairs + 1 with phantom)
#define SITE_F 8192     // elements per site tensor (64*2*64)
#define PAIR_U16 16384  // ushorts per pair fragment block
#define PAIR_F 8192     // same block viewed as floats

// ---- async global->LDS ----
__device__ __forceinline__ void gld_lds16(const float* g, float* l) {
  __builtin_amdgcn_global_load_lds(
      (const __attribute__((address_space(1))) unsigned int*)g,
      (__attribute__((address_space(3))) unsigned int*)l, 16, 0, 0);
}

__device__ __forceinline__ unsigned short f2bf(float v) {
  const unsigned uu = __builtin_bit_cast(unsigned, v);
  return (unsigned short)((uu + 0x7FFFu + ((uu >> 16) & 1u)) >> 16);  // RNE
}

// ---- one-shot: pair transfer matrices D = A_i*A_j - I (verbatim R16) ----
__global__ __launch_bounds__(256) void prep_pair(const float* __restrict__ lsrc,
                                                 const float* __restrict__ rsrc,
                                                 unsigned short* __restrict__ Wp) {
  __shared__ float X[8192];
  __shared__ float YT[8192];
  const int pair = blockIdx.x, dir = blockIdx.y;
  const int tid = threadIdx.x;
  unsigned short* dst = Wp + ((size_t)dir * NP + pair) * PAIR_U16;
  const bool ph = (pair == NP - 1);

  const float* Xg;
  const float* Yg = nullptr;
  if (dir == 0) {
    Xg = lsrc + (size_t)(2 * pair) * SITE_F;
    if (!ph) Yg = lsrc + (size_t)(2 * pair + 1) * SITE_F;
  } else {
    const int s1 = 510 - 2 * pair;
    if (!ph) {
      Xg = rsrc + (size_t)(s1 - 1) * SITE_F;
      Yg = rsrc + (size_t)s1 * SITE_F;
    } else {
      Xg = rsrc;
    }
  }
#pragma unroll
  for (int q8 = 0; q8 < 8; q8++)
    *(vf4*)&X[(q8 * 256 + tid) * 4] = *(const vf4*)&Xg[(q8 * 256 + tid) * 4];
  if (!ph) {
#pragma unroll
    for (int q8 = 0; q8 < 8; q8++) {
      const int e = (q8 * 256 + tid) * 4;
      const vf4 v = *(const vf4*)&Yg[e];
      const int A = e >> 7, B = (e >> 6) & 1, C = e & 63;
#pragma unroll
      for (int k2 = 0; k2 < 4; k2++)
        YT[(B * 64 + C + k2) * 64 + A] = v[k2];
    }
  }
  __syncthreads();

  const int kk = tid >> 2;
  const int p = (tid >> 1) & 1, q = tid & 1;
  const int s = 2 * (kk >> 4) + p;
  const int g = (kk >> 2) & 3;
  const int j = 2 * (kk & 3) + q;

  vf4 row[16];
  if (dir == 0) {
#pragma unroll
    for (int w = 0; w < 16; w++)
      row[w] = *(const vf4*)&X[kk * 128 + p * 64 + w * 4];
  } else if (!ph) {
#pragma unroll
    for (int w = 0; w < 16; w++)
      row[w] = *(const vf4*)&YT[(p * 64 + kk) * 64 + w * 4];
  }

  for (int mm = 0; mm < 64; mm++) {
    float val;
    if (dir == 0) {
      if (!ph) {
        float d = 0.f;
#pragma unroll
        for (int w = 0; w < 16; w++) {
          const vf4 y = *(const vf4*)&YT[(q * 64 + mm) * 64 + w * 4];
          d += row[w][0] * y[0] + row[w][1] * y[1] +
               row[w][2] * y[2] + row[w][3] * y[3];
        }
        val = d - ((kk == mm) ? 1.f : 0.f);
      } else {
        val = row[mm >> 2][mm & 3] - ((kk == mm) ? 1.f : 0.f);
      }
    } else {
      if (!ph) {
        float d = 0.f;
#pragma unroll
        for (int w = 0; w < 16; w++) {
          const vf4 xv = *(const vf4*)&X[mm * 128 + q * 64 + w * 4];
          d += xv[0] * row[w][0] + xv[1] * row[w][1] +
               xv[2] * row[w][2] + xv[3] * row[w][3];
        }
        val = d - ((mm == kk) ? 1.f : 0.f);
      } else {
        val = X[mm * 128 + p * 64 + kk] - ((mm == kk) ? 1.f : 0.f);
      }
    }
    const int mt = mm >> 4, c = mm & 15;
    dst[(size_t)(((mt * 8 + s) * 64) + (g << 4) + c) * 8 + j] = f2bf(val);
  }
}

// ---- one-shot: pack center C[l][r][o] into per-o A-frags (verbatim) ----
__global__ __launch_bounds__(256) void prep2(const float* __restrict__ center,
                                             unsigned short* __restrict__ Cf) {
  __shared__ float S[4096];
  const int o = blockIdx.x;
  const int tid = threadIdx.x;
#pragma unroll
  for (int k = 0; k < 16; k++) {
    const int idx = k * 256 + tid;
    S[idx] = center[(size_t)idx * 128 + o];
  }
  __syncthreads();
#pragma unroll
  for (int q = 0; q < 2; q++) {
    const int slot = q * 256 + tid;
    const int lane = slot & 63, f = slot >> 6;
    const int mt = f >> 1, s = f & 1;
    const int g = lane >> 4, c = lane & 15;
    const int l = 16 * mt + c;
    ushort8 t;
#pragma unroll
    for (int j = 0; j < 8; j++) {
      const int r = 32 * s + 8 * g + j;
      t[j] = f2bf(S[l * 64 + r]);
    }
    *(ushort8*)&Cf[(size_t)((o * 8 + f) * 64 + lane) * 8] = t;
  }
}

// ---- stage one pair (32KB) with 256 threads (8 gld_lds16 each) ----
#define STAGE(P, SL)                                                           \
  {                                                                            \
    const float* src_ = Wf + (size_t)(P) * PAIR_F;                             \
    float* d_ = &ring[SL][0];                                                  \
    _Pragma("unroll")                                                          \
    for (int q8 = 0; q8 < 8; q8++)                                             \
      gld_lds16(src_ + q8 * 1024 + tid * 4, d_ + q8 * 1024 + tid * 4);         \
  }

// ---- sweep: 256 blocks x 4 waves; 2 chains/block, m-split across 2 waves --
// raw s_barrier + counted vmcnt(16) (m201 discipline); ring-3 W pairs;
// e2 half-exchange via parity-dbuf LDS; deferred exact-pow2 rescale.
__global__ __launch_bounds__(256, 1) void sweep(const float* __restrict__ x,
                                                const float* __restrict__ left0,
                                                const float* __restrict__ right_last,
                                                const unsigned short* __restrict__ Wp,
                                                float* __restrict__ envL,
                                                float* __restrict__ envR,
                                                unsigned short* __restrict__ Rb16) {
  __shared__ float ring[3][PAIR_F];          // 96 KB W-pair ring
  __shared__ vi4 e2x[2][2][8][64];           // 32 KB [ch][parity][s][lane]
  __shared__ float nssx[2][2];               // [ch][h]
  const int bid = blockIdx.x;
  const int xcd = bid & 7;
  const int dir = xcd >> 2;
  const int slot = (xcd & 3) * 32 + (bid >> 3);
  const int tid = threadIdx.x;
  const int wave = tid >> 6;
  const int lane = tid & 63;
  const int ch = wave >> 1, h = wave & 1;
  const int g_ = lane >> 4, c = lane & 15;
  const int b = (slot * 2 + ch) * 16 + c;
  const float* xrow = x + (size_t)b * LL;

  const float* Wf = (const float*)(Wp + (size_t)dir * NP * PAIR_U16);

  // ---- u-half init (mt_global = 2h+lm); full-norm via LDS exchange ----
  vf4 u[2];
  {
    const float x0 = xrow[dir ? (LL - 1) : 0];
    const float qrev = 0.25f * x0;
    float cs, sn;
    asm("v_cos_f32 %0, %1" : "=v"(cs) : "v"(qrev));
    asm("v_sin_f32 %0, %1" : "=v"(sn) : "v"(qrev));
#pragma unroll
    for (int lm = 0; lm < 2; lm++)
#pragma unroll
      for (int r = 0; r < 4; r++) {
        const int n = 16 * (2 * h + lm) + 4 * g_ + r;
        const float w0 = dir ? right_last[n * 2] : left0[n];
        const float w1 = dir ? right_last[n * 2 + 1] : left0[64 + n];
        u[lm][r] = cs * w0 + sn * w1;
      }
    float ss = 0.f;
#pragma unroll
    for (int lm = 0; lm < 2; lm++)
#pragma unroll
      for (int r = 0; r < 4; r++) ss += u[lm][r] * u[lm][r];
    ss += __shfl_xor(ss, 16);
    ss += __shfl_xor(ss, 32);
    if (lane == 0) nssx[ch][h] = ss;
    asm volatile("s_waitcnt lgkmcnt(0)" ::: "memory");
    __builtin_amdgcn_sched_barrier(0);
    __builtin_amdgcn_s_barrier();
    const float tot = nssx[ch][0] + nssx[ch][1];
    const float a0 = 1.f / (sqrtf(tot) + 1e-8f);
#pragma unroll
    for (int lm = 0; lm < 2; lm++)
#pragma unroll
      for (int r = 0; r < 4; r++) u[lm][r] *= a0;
  }

  // trig for pair 0
  float ci, si, cj, sj;
  {
    const float qi = 0.25f * xrow[dir ? 1022 : 1];
    const float qj = 0.25f * xrow[dir ? 1021 : 2];
    asm("v_cos_f32 %0, %1" : "=v"(ci) : "v"(qi));
    asm("v_sin_f32 %0, %1" : "=v"(si) : "v"(qi));
    asm("v_cos_f32 %0, %1" : "=v"(cj) : "v"(qj));
    asm("v_sin_f32 %0, %1" : "=v"(sj) : "v"(qj));
  }

  STAGE(0, 0)
  STAGE(1, 1)

  // e2-own(pair 0) -> regs + LDS parity 0
  vi4 e2A[4];
  {
    const float w00 = ci * cj, w01 = ci * sj, w10 = si * cj, w11 = si * sj;
#pragma unroll
    for (int k = 0; k < 4; k++) {
      const float wa = (k & 1) ? w10 : w00;
      const float wb = (k & 1) ? w11 : w01;
      int pk[4];
#pragma unroll
      for (int t = 0; t < 4; t++) {
        const float uv = u[k >> 1][t];
        const float f0 = uv * wa, f1 = uv * wb;
        int pp;
        asm("v_cvt_pk_bf16_f32 %0, %1, %2" : "=v"(pp) : "v"(f0), "v"(f1));
        pk[t] = pp;
      }
      e2A[k] = (vi4){pk[0], pk[1], pk[2], pk[3]};
      e2x[ch][0][4 * h + k][lane] = e2A[k];
    }
  }

  int sl = 0;   // ring slot of pair p
  for (int p = 0; p < NP; p++) {
    asm volatile("s_waitcnt lgkmcnt(0)" ::: "memory");
    __builtin_amdgcn_sched_barrier(0);
    __builtin_amdgcn_s_barrier();             // barrier(p): e2(p) + ring sync
    const int sl2 = (sl == 0) ? 2 : (sl - 1); // (p+2)%3
    if (p + 2 < NP) STAGE(p + 2, sl2)
    asm volatile("s_waitcnt vmcnt(16)" ::: "memory");
    __builtin_amdgcn_sched_barrier(0);

    // FC: my m-half of pair p (16 frags)
    vf4 FC[16];
    {
      const float* rb = &ring[sl][0];
#pragma unroll
      for (int q = 0; q < 16; q++)
        FC[q] = *(const vf4*)&rb[(16 * h + q) * 256 + lane * 4];
    }
    // x for pair p+1 (compiler loads; precise compiler waits)
    float xiN = 0.f, xjN = 0.f;
    if (p + 1 < NP) {
      xiN = xrow[dir ? (1022 - 2 * (p + 1)) : (1 + 2 * (p + 1))];
      xjN = (p + 1 == NP - 1) ? 0.f
                              : xrow[dir ? (1021 - 2 * (p + 1)) : (2 + 2 * (p + 1))];
    }
    // e2 other half
    vi4 eo[4];
#pragma unroll
    for (int k = 0; k < 4; k++) eo[k] = e2x[ch][p & 1][4 * (1 - h) + k][lane];

    const float keff = (ci + si) * (cj + sj);
    vf4 accA[2], accB[2];
#pragma unroll
    for (int lm = 0; lm < 2; lm++) {
      vf4 z;
      z[0] = keff * u[lm][0]; z[1] = keff * u[lm][1];
      z[2] = keff * u[lm][2]; z[3] = keff * u[lm][3];
      accA[lm] = z;
      accB[lm] = (vf4){0.f, 0.f, 0.f, 0.f};
    }
#pragma unroll
    for (int s = 0; s < 8; s++) {
      const vi4 ев = ((s >> 2) == h) ? e2A[s & 3] : eo[s & 3];
      const short8 e2s = __builtin_bit_cast(short8, ев);
#pragma unroll
      for (int lm = 0; lm < 2; lm++) {
        if (s < 4)
          accA[lm] = __builtin_amdgcn_mfma_f32_16x16x32_bf16(
              __builtin_bit_cast(short8, FC[lm * 8 + s]), e2s, accA[lm], 0, 0, 0);
        else
          accB[lm] = __builtin_amdgcn_mfma_f32_16x16x32_bf16(
              __builtin_bit_cast(short8, FC[lm * 8 + s]), e2s, accB[lm], 0, 0, 0);
      }
    }
#pragma unroll
    for (int lm = 0; lm < 2; lm++) u[lm] = accA[lm] + accB[lm];

    if ((p & 3) == 3) {          // publish half-norm
      float nss = 0.f;
#pragma unroll
      for (int lm = 0; lm < 2; lm++)
#pragma unroll
        for (int r = 0; r < 4; r++) nss += u[lm][r] * u[lm][r];
      nss += __shfl_xor(nss, 16);
      nss += __shfl_xor(nss, 32);
      if (lane == 0) nssx[ch][h] = nss;
    }
    if ((p & 3) == 0 && p > 0) { // deferred exact-pow2 rescale
      const float tot = nssx[ch][0] + nssx[ch][1];
      const int eb = (__float_as_int(tot) >> 23) & 0xFF;
      const float alpha = __int_as_float((127 - ((eb - 127) >> 1)) << 23);
#pragma unroll
      for (int lm = 0; lm < 2; lm++)
#pragma unroll
        for (int r = 0; r < 4; r++) u[lm][r] *= alpha;
    }

    if (p + 1 < NP) {
      const float qi = 0.25f * xiN, qj = 0.25f * xjN;
      float c_, s_;
      asm("v_cos_f32 %0, %1" : "=v"(c_) : "v"(qi));
      asm("v_sin_f32 %0, %1" : "=v"(s_) : "v"(qi));
      ci = c_; si = s_;
      asm("v_cos_f32 %0, %1" : "=v"(c_) : "v"(qj));
      asm("v_sin_f32 %0, %1" : "=v"(s_) : "v"(qj));
      cj = c_; sj = s_;
      // e2-own(p+1) -> regs + LDS parity (p+1)&1
      const float w00 = ci * cj, w01 = ci * sj, w10 = si * cj, w11 = si * sj;
#pragma unroll
      for (int k = 0; k < 4; k++) {
        const float wa = (k & 1) ? w10 : w00;
        const float wb = (k & 1) ? w11 : w01;
        int pk[4];
#pragma unroll
        for (int t = 0; t < 4; t++) {
          const float uv = u[k >> 1][t];
          const float f0 = uv * wa, f1 = uv * wb;
          int pp;
          asm("v_cvt_pk_bf16_f32 %0, %1, %2" : "=v"(pp) : "v"(f0), "v"(f1));
          pk[t] = pp;
        }
        e2A[k] = (vi4){pk[0], pk[1], pk[2], pk[3]};
        e2x[ch][(p + 1) & 1][4 * h + k][lane] = e2A[k];
      }
    }
    sl = (sl == 2) ? 0 : (sl + 1);
  }

  // ---- final full normalize (cross-wave) + store ----
  {
    float nss = 0.f;
#pragma unroll
    for (int lm = 0; lm < 2; lm++)
#pragma unroll
      for (int r = 0; r < 4; r++) nss += u[lm][r] * u[lm][r];
    nss += __shfl_xor(nss, 16);
    nss += __shfl_xor(nss, 32);
    if (lane == 0) nssx[ch][h] = nss;
    asm volatile("s_waitcnt lgkmcnt(0)" ::: "memory");
    __builtin_amdgcn_sched_barrier(0);
    __builtin_amdgcn_s_barrier();
    const float tot = nssx[ch][0] + nssx[ch][1];
    const float alpha = 1.f / (sqrtf(tot) + 1e-8f);

    float* eo = (dir ? envR : envL) + (size_t)b * 64;
#pragma unroll
    for (int lm = 0; lm < 2; lm++) {
      vf4 v;
#pragma unroll
      for (int r = 0; r < 4; r++) v[r] = u[lm][r] * alpha;
      *(vf4*)&eo[16 * (2 * h + lm) + 4 * g_] = v;
      if (dir) {
        int p01, p23;
        asm("v_cvt_pk_bf16_f32 %0, %1, %2" : "=v"(p01) : "v"(v[0]), "v"(v[1]));
        asm("v_cvt_pk_bf16_f32 %0, %1, %2" : "=v"(p23) : "v"(v[2]), "v"(v[3]));
        *(vi2*)&Rb16[(size_t)b * 64 + 16 * (2 * h + lm) + 4 * g_] = (vi2){p01, p23};
      }
    }
  }
}

// ---- center contraction via MFMA (verbatim R16) ----
__global__ __launch_bounds__(256) void centerk2(const float* __restrict__ envL,
                                                const unsigned short* __restrict__ Rb16,
                                                const unsigned short* __restrict__ Cf,
                                                float* __restrict__ Pp) {
  const int b0 = blockIdx.x * 16;
  const int tid = threadIdx.x;
  const int wave = tid >> 6;
  const int lane = tid & 63;
  const int g = lane >> 4, c = lane & 15;

  short8 rf[2];
#pragma unroll
  for (int s = 0; s < 2; s++)
    rf[s] = __builtin_bit_cast(short8,
        *(const ushort8*)&Rb16[(size_t)(b0 + c) * 64 + 32 * s + 8 * g]);

  vf4 Lv[4];
#pragma unroll
  for (int mt = 0; mt < 4; mt++)
    Lv[mt] = *(const vf4*)&envL[(size_t)(b0 + c) * 64 + 16 * mt + 4 * g];

  for (int oi = 0; oi < 32; oi++) {
    const int o = wave * 32 + oi;
    const unsigned short* cb = Cf + (size_t)(o * 8) * 64 * 8;
    vf4 acc[4];
#pragma unroll
    for (int mt = 0; mt < 4; mt++) {
      const short8 a0 = __builtin_bit_cast(short8,
          *(const ushort8*)&cb[(size_t)((mt * 2 + 0) * 64 + lane) * 8]);
      const short8 a1 = __builtin_bit_cast(short8,
          *(const ushort8*)&cb[(size_t)((mt * 2 + 1) * 64 + lane) * 8]);
      vf4 z = {0.f, 0.f, 0.f, 0.f};
      z = __builtin_amdgcn_mfma_f32_16x16x32_bf16(a0, rf[0], z, 0, 0, 0);
      z = __builtin_amdgcn_mfma_f32_16x16x32_bf16(a1, rf[1], z, 0, 0, 0);
      acc[mt] = z;
    }
    float ps = 0.f;
#pragma unroll
    for (int mt = 0; mt < 4; mt++)
#pragma unroll
      for (int r = 0; r < 4; r++) ps += Lv[mt][r] * acc[mt][r];
    ps += __shfl_xor(ps, 16);
    ps += __shfl_xor(ps, 32);
    if (g == 0) Pp[(size_t)(b0 + c) * 128 + o] = ps;
  }
}

// ---- row-normalize Pp -> out ----
__global__ __launch_bounds__(256) void combinek2(const float* __restrict__ P,
                                                 float* __restrict__ out) {
  const int row = blockIdx.x * 8 + (threadIdx.x >> 5);
  const int o0 = (threadIdx.x & 31) * 4;
  vf4 v = *(const vf4*)&P[(size_t)row * 128 + o0];
  float ss = v[0] * v[0] + v[1] * v[1] + v[2] * v[2] + v[3] * v[3];
#pragma unroll
  for (int m = 1; m < 32; m <<= 1) ss += __shfl_xor(ss, m);
  const float inv = 1.f / fmaxf(sqrtf(ss), 1e-12f);
  v *= inv;
  *(vf4*)&out[(size_t)row * 128 + o0] = v;
}

extern "C" void kernel_launch(void* const* d_in, const int* in_sizes, int n_in,
                              void* d_out, int out_size, void* d_ws, size_t ws_size,
                              hipStream_t stream) {
  const float* x = (const float*)d_in[0];
  const float* left0 = (const float*)d_in[1];
  const float* left_rest = (const float*)d_in[2];
  const float* center = (const float*)d_in[3];
  const float* right_rest = (const float*)d_in[4];
  const float* right_last = (const float*)d_in[5];
  float* out = (float*)d_out;

  char* wsb = (char*)d_ws;
  unsigned short* Wp = (unsigned short*)wsb;                  // 16.8 MB
  float* envL = (float*)(Wp + (size_t)2 * NP * PAIR_U16);     // 1 MB
  float* envR = envL + (size_t)BBATCH * 64;                   // 1 MB
  unsigned short* Rb16 = (unsigned short*)(envR + (size_t)BBATCH * 64);  // 0.5 MB
  unsigned short* Cf = Rb16 + (size_t)BBATCH * 64;            // 1 MB
  float* Pp = (float*)(Cf + (size_t)OO * 8 * 64 * 8);         // 2 MB

  hipLaunchKernelGGL(prep_pair, dim3(NP, 2), dim3(256), 0, stream,
                     left_rest, right_rest, Wp);
  hipLaunchKernelGGL(prep2, dim3(OO), dim3(256), 0, stream, center, Cf);
  hipLaunchKernelGGL(sweep, dim3(256), dim3(256), 0, stream,
                     x, left0, right_last, Wp, envL, envR, Rb16);
  hipLaunchKernelGGL(centerk2, dim3(BBATCH / 16), dim3(256), 0, stream,
                     envL, Rb16, Cf, Pp);
  hipLaunchKernelGGL(combinek2, dim3(BBATCH / 8), dim3(256), 0, stream, Pp, out);
}

// Round 18
// 414.781 us; speedup vs baseline: 1.0523x; 1.0523x over previous
//
#include <hip/hip_runtime.h>

typedef float vf4 __attribute__((ext_vector_type(4)));
typedef int vi4 __attribute__((ext_vector_type(4)));
typedef int vi2 __attribute__((ext_vector_type(2)));
typedef short short8 __attribute__((ext_vector_type(8)));
typedef unsigned short ushort8 __attribute__((ext_vector_type(8)));

#define LL 1024
#define OO 128
#define BBATCH 4096
#define NS 511          // sites per sweep
#define SITE_F 8192     // elements per site tensor (64*2*64)

// ---- async global->LDS ----
__device__ __forceinline__ void gld_lds16(const float* g, float* l) {
  __builtin_amdgcn_global_load_lds(
      (const __attribute__((address_space(1))) unsigned int*)g,
      (__attribute__((address_space(3))) unsigned int*)l, 16, 0, 0);
}

__device__ __forceinline__ unsigned short f2bf(float v) {
  const unsigned uu = __builtin_bit_cast(unsigned, v);
  return (unsigned short)((uu + 0x7FFFu + ((uu >> 16) & 1u)) >> 16);  // RNE
}

// ---- one-shot: build bf16 16x16x32-frag-major N = A - I for both sweeps ----
// layout: W[site][f][lane][j] bf16, f = mt*4+s (mt=M-tile 0..3, s=K-step 0..3)
// A elem: m = 16*mt + (lane&15); k = 32*s + 8*(lane>>4) + j  (k = 2*env_in + p)
// right buffer is site-reversed so the sweep always walks ascending.
__global__ __launch_bounds__(256) void prep(const float* __restrict__ lsrc,
                                            const float* __restrict__ rsrc,
                                            unsigned short* __restrict__ Wl,
                                            unsigned short* __restrict__ Wr) {
  __shared__ float S[SITE_F];
  const int site = blockIdx.x;
  const int dir = blockIdx.y;
  const int tid = threadIdx.x;
  const float* src = (dir ? rsrc : lsrc) + (size_t)site * SITE_F;
  unsigned short* dst = dir ? (Wr + (size_t)(NS - 1 - site) * SITE_F)
                            : (Wl + (size_t)site * SITE_F);
#pragma unroll
  for (int m = 0; m < 8; m++)
    *(vf4*)&S[(m * 256 + tid) * 4] = *(const vf4*)&src[(m * 256 + tid) * 4];
  __syncthreads();
#pragma unroll
  for (int q = 0; q < 4; q++) {
    const int slot = q * 256 + tid;           // 0..1023 = f*64 + lane
    const int lane = slot & 63, f = slot >> 6;
    const int mt = f >> 2, s = f & 3;
    const int g = lane >> 4, c = lane & 15;
    const int m = 16 * mt + c;
    ushort8 t;
#pragma unroll
    for (int j = 0; j < 8; j++) {
      const int k = 32 * s + 8 * g + j;
      float v;
      if (dir == 0) {
        const int l = k >> 1, p = k & 1;
        v = S[l * 128 + p * 64 + m] - ((m == l) ? 1.f : 0.f);
      } else {
        const int r = k >> 1, p = k & 1;
        v = S[m * 128 + p * 64 + r] - ((m == r) ? 1.f : 0.f);
      }
      t[j] = f2bf(v);
    }
    *(ushort8*)&dst[(size_t)slot * 8] = t;
  }
}

// ---- one-shot: pack center C[l][r][o] into per-o A-frags (bf16) ----
__global__ __launch_bounds__(256) void prep2(const float* __restrict__ center,
                                             unsigned short* __restrict__ Cf) {
  __shared__ float S[4096];        // C[:,:,o] slab, [l*64+r]
  const int o = blockIdx.x;
  const int tid = threadIdx.x;
#pragma unroll
  for (int k = 0; k < 16; k++) {
    const int idx = k * 256 + tid;
    S[idx] = center[(size_t)idx * 128 + o];
  }
  __syncthreads();
#pragma unroll
  for (int q = 0; q < 2; q++) {
    const int slot = q * 256 + tid;           // 0..511 = f*64 + lane
    const int lane = slot & 63, f = slot >> 6;
    const int mt = f >> 1, s = f & 1;
    const int g = lane >> 4, c = lane & 15;
    const int l = 16 * mt + c;
    ushort8 t;
#pragma unroll
    for (int j = 0; j < 8; j++) {
      const int r = 32 * s + 8 * g + j;
      t[j] = f2bf(S[l * 64 + r]);
    }
    *(ushort8*)&Cf[(size_t)((o * 8 + f) * 64 + lane) * 8] = t;
  }
}

// ---- stage one 2-site group (32KB) with 64 threads (32 gld_lds16) ----
#define STAGE_GROUP(G, BUF)                                                    \
  {                                                                            \
    _Pragma("unroll")                                                          \
    for (int s2 = 0; s2 < 2; s2++) {                                           \
      int st_ = (G) * 2 + s2;                                                  \
      if (st_ > NS - 1) st_ = NS - 1;                                          \
      const float* src_ = Wf + (size_t)st_ * 4096;                             \
      float* d_ = &ring[BUF][s2][0];                                           \
      _Pragma("unroll")                                                        \
      for (int q = 0; q < 16; q++)                                             \
        gld_lds16(src_ + q * 256 + lane * 4, d_ + q * 256 + lane * 4);         \
    }                                                                          \
  }

// ---- per-site body: W frags from resident LDS, compiler scheduling ----
#define BODY(I, BUF, S2)                                                       \
  {                                                                            \
    const float* rb = &ring[BUF][S2][0];                                       \
    vf4 FC[16];                                                                \
    _Pragma("unroll")                                                          \
    for (int q = 0; q < 16; q++)                                               \
      FC[q] = *(const vf4*)&rb[(q * 64 + lane) * 4];                           \
    const int nI = (I) + 1;                                                    \
    float xn = 0.f;                                                            \
    if (nI <= NS - 1) xn = xrow[dir ? (1022 - nI) : (1 + nI)];                 \
    short8 e2[4];                                                              \
    _Pragma("unroll")                                                          \
    for (int s = 0; s < 4; s++) {                                              \
      int pk[4];                                                               \
      _Pragma("unroll")                                                        \
      for (int t = 0; t < 4; t++) {                                            \
        const float f0 = u[s][t] * CS, f1 = u[s][t] * SN;                      \
        int p;                                                                 \
        asm("v_cvt_pk_bf16_f32 %0, %1, %2" : "=v"(p) : "v"(f0), "v"(f1));      \
        pk[t] = p;                                                             \
      }                                                                        \
      e2[s] = __builtin_bit_cast(short8, (vi4){pk[0], pk[1], pk[2], pk[3]});   \
    }                                                                          \
    const float keff = CS + SN;                                                \
    vf4 accA[4], accB[4];                                                      \
    _Pragma("unroll")                                                          \
    for (int mt = 0; mt < 4; mt++) {                                           \
      vf4 z;                                                                   \
      z[0] = keff * u[mt][0]; z[1] = keff * u[mt][1];                          \
      z[2] = keff * u[mt][2]; z[3] = keff * u[mt][3];                          \
      accA[mt] = z;                                                            \
      accB[mt] = (vf4){0.f, 0.f, 0.f, 0.f};                                    \
    }                                                                          \
    _Pragma("unroll")                                                          \
    for (int mt = 0; mt < 4; mt++) {                                           \
      accA[mt] = __builtin_amdgcn_mfma_f32_16x16x32_bf16(                      \
          __builtin_bit_cast(short8, FC[mt * 4 + 0]), e2[0], accA[mt], 0,0,0); \
      accA[mt] = __builtin_amdgcn_mfma_f32_16x16x32_bf16(                      \
          __builtin_bit_cast(short8, FC[mt * 4 + 1]), e2[1], accA[mt], 0,0,0); \
      accB[mt] = __builtin_amdgcn_mfma_f32_16x16x32_bf16(                      \
          __builtin_bit_cast(short8, FC[mt * 4 + 2]), e2[2], accB[mt], 0,0,0); \
      accB[mt] = __builtin_amdgcn_mfma_f32_16x16x32_bf16(                      \
          __builtin_bit_cast(short8, FC[mt * 4 + 3]), e2[3], accB[mt], 0,0,0); \
    }                                                                          \
    _Pragma("unroll")                                                          \
    for (int mt = 0; mt < 4; mt++) u[mt] = accA[mt] + accB[mt];                \
    if (nI <= NS - 1) {                                                        \
      const float qrev = 0.25f * xn; /* cos(pi/2 x)=cos(2pi*(x/4)) */          \
      float c_, s_;                                                            \
      asm("v_cos_f32 %0, %1" : "=v"(c_) : "v"(qrev));                          \
      asm("v_sin_f32 %0, %1" : "=v"(s_) : "v"(qrev));                          \
      CS = c_;                                                                 \
      SN = s_;                                                                 \
    }                                                                          \
    if (((I) & 7) == 7) { /* exact pow2 rescale, keeps fp32 in range */        \
      float nss = 0.f;                                                         \
      _Pragma("unroll")                                                        \
      for (int mt = 0; mt < 4; mt++)                                           \
        _Pragma("unroll")                                                      \
        for (int r = 0; r < 4; r++) nss += u[mt][r] * u[mt][r];                \
      nss += __shfl_xor(nss, 16);                                              \
      nss += __shfl_xor(nss, 32);                                              \
      const int eb = (__float_as_int(nss) >> 23) & 0xFF;                       \
      const float alpha = __int_as_float((127 - ((eb - 127) >> 1)) << 23);     \
      _Pragma("unroll")                                                        \
      for (int mt = 0; mt < 4; mt++)                                           \
        _Pragma("unroll")                                                      \
        for (int r = 0; r < 4; r++) u[mt][r] *= alpha;                         \
    }                                                                          \
  }

// ---- sweep: 512 INDEPENDENT 1-wave blocks (2/CU); 16-sample chains; ----
// group = 2 sites (32KB), double-buffered (64KB), 1 syncthreads per group.
// XCD swizzle: XCDs 0-3 -> dir 0, XCDs 4-7 -> dir 1.
__global__ __launch_bounds__(64, 1) void sweep(const float* __restrict__ x,
                                               const float* __restrict__ left0,
                                               const float* __restrict__ right_last,
                                               const unsigned short* __restrict__ Wl,
                                               const unsigned short* __restrict__ Wr,
                                               float* __restrict__ envL,
                                               float* __restrict__ envR,
                                               unsigned short* __restrict__ Rb16) {
  __shared__ float ring[2][2][4096];   // 2 groups x 2 sites x 16KB = 64KB
  const int bid = blockIdx.x;          // 0..511
  const int xcd = bid & 7;
  const int dir = xcd >> 2;
  const int pr = (xcd & 3) * 64 + (bid >> 3);   // 0..255 within dir
  const int lane = threadIdx.x;
  const int g_ = lane >> 4, c = lane & 15;
  const int b = pr * 16 + c;
  const float* xrow = x + (size_t)b * LL;

  const float* Wf = (const float*)(dir ? Wr : Wl);

  // init env (fp32, exact normalize)
  vf4 u[4];
  {
    const float x0 = xrow[dir ? (LL - 1) : 0];
    const float qrev = 0.25f * x0;
    float cs, sn;
    asm("v_cos_f32 %0, %1" : "=v"(cs) : "v"(qrev));
    asm("v_sin_f32 %0, %1" : "=v"(sn) : "v"(qrev));
#pragma unroll
    for (int mt = 0; mt < 4; mt++)
#pragma unroll
      for (int r = 0; r < 4; r++) {
        const int n = 16 * mt + 4 * g_ + r;
        const float w0 = dir ? right_last[n * 2] : left0[n];
        const float w1 = dir ? right_last[n * 2 + 1] : left0[64 + n];
        u[mt][r] = cs * w0 + sn * w1;
      }
    float ss = 0.f;
#pragma unroll
    for (int mt = 0; mt < 4; mt++)
#pragma unroll
      for (int r = 0; r < 4; r++) ss += u[mt][r] * u[mt][r];
    ss += __shfl_xor(ss, 16);
    ss += __shfl_xor(ss, 32);
    const float a0 = 1.f / (sqrtf(ss) + 1e-8f);
#pragma unroll
    for (int mt = 0; mt < 4; mt++)
#pragma unroll
      for (int r = 0; r < 4; r++) u[mt][r] *= a0;
  }

  float CS, SN;
  {
    const float q0 = 0.25f * xrow[dir ? 1022 : 1];
    asm("v_cos_f32 %0, %1" : "=v"(CS) : "v"(q0));
    asm("v_sin_f32 %0, %1" : "=v"(SN) : "v"(q0));
  }

  STAGE_GROUP(0, 0)
  __syncthreads();

  // ---- main loop: 255 full groups (sites 0..509), tail site 510 ----
  for (int g = 0; g < 255; g++) {
    const int buf = g & 1;
    STAGE_GROUP(g + 1, buf ^ 1)     // prefetch next group while computing
    const int i0 = g * 2;
    BODY(i0 + 0, buf, 0)
    BODY(i0 + 1, buf, 1)
    __syncthreads();                // drains stage(g+1); buf reusable
  }
  BODY(510, 1, 0)

  // final exact normalize + store (f32 env + bf16 copy for centerk2)
  float nss = 0.f;
#pragma unroll
  for (int mt = 0; mt < 4; mt++)
#pragma unroll
    for (int r = 0; r < 4; r++) nss += u[mt][r] * u[mt][r];
  nss += __shfl_xor(nss, 16);
  nss += __shfl_xor(nss, 32);
  const float alpha = 1.f / (sqrtf(nss) + 1e-8f);

  float* eo = (dir ? envR : envL) + (size_t)b * 64;
#pragma unroll
  for (int mt = 0; mt < 4; mt++) {
    vf4 v;
#pragma unroll
    for (int r = 0; r < 4; r++) v[r] = u[mt][r] * alpha;
    *(vf4*)&eo[16 * mt + 4 * g_] = v;
    if (dir) {
      int p01, p23;
      asm("v_cvt_pk_bf16_f32 %0, %1, %2" : "=v"(p01) : "v"(v[0]), "v"(v[1]));
      asm("v_cvt_pk_bf16_f32 %0, %1, %2" : "=v"(p23) : "v"(v[2]), "v"(v[3]));
      *(vi2*)&Rb16[(size_t)b * 64 + 16 * mt + 4 * g_] = (vi2){p01, p23};
    }
  }
}

// ---- center contraction via MFMA: out[b,o] = L[b,:]·(C_o·R[b,:]^T) ----
__global__ __launch_bounds__(256) void centerk2(const float* __restrict__ envL,
                                                const unsigned short* __restrict__ Rb16,
                                                const unsigned short* __restrict__ Cf,
                                                float* __restrict__ Pp) {
  const int b0 = blockIdx.x * 16;
  const int tid = threadIdx.x;
  const int wave = tid >> 6;
  const int lane = tid & 63;
  const int g = lane >> 4, c = lane & 15;

  short8 rf[2];
#pragma unroll
  for (int s = 0; s < 2; s++)
    rf[s] = __builtin_bit_cast(short8,
        *(const ushort8*)&Rb16[(size_t)(b0 + c) * 64 + 32 * s + 8 * g]);

  vf4 Lv[4];
#pragma unroll
  for (int mt = 0; mt < 4; mt++)
    Lv[mt] = *(const vf4*)&envL[(size_t)(b0 + c) * 64 + 16 * mt + 4 * g];

  for (int oi = 0; oi < 32; oi++) {
    const int o = wave * 32 + oi;
    const unsigned short* cb = Cf + (size_t)(o * 8) * 64 * 8;
    vf4 acc[4];
#pragma unroll
    for (int mt = 0; mt < 4; mt++) {
      const short8 a0 = __builtin_bit_cast(short8,
          *(const ushort8*)&cb[(size_t)((mt * 2 + 0) * 64 + lane) * 8]);
      const short8 a1 = __builtin_bit_cast(short8,
          *(const ushort8*)&cb[(size_t)((mt * 2 + 1) * 64 + lane) * 8]);
      vf4 z = {0.f, 0.f, 0.f, 0.f};
      z = __builtin_amdgcn_mfma_f32_16x16x32_bf16(a0, rf[0], z, 0, 0, 0);
      z = __builtin_amdgcn_mfma_f32_16x16x32_bf16(a1, rf[1], z, 0, 0, 0);
      acc[mt] = z;
    }
    float ps = 0.f;
#pragma unroll
    for (int mt = 0; mt < 4; mt++)
#pragma unroll
      for (int r = 0; r < 4; r++) ps += Lv[mt][r] * acc[mt][r];
    ps += __shfl_xor(ps, 16);
    ps += __shfl_xor(ps, 32);
    if (g == 0) Pp[(size_t)(b0 + c) * 128 + o] = ps;
  }
}

// ---- row-normalize Pp -> out ----
__global__ __launch_bounds__(256) void combinek2(const float* __restrict__ P,
                                                 float* __restrict__ out) {
  const int row = blockIdx.x * 8 + (threadIdx.x >> 5);
  const int o0 = (threadIdx.x & 31) * 4;
  vf4 v = *(const vf4*)&P[(size_t)row * 128 + o0];
  float ss = v[0] * v[0] + v[1] * v[1] + v[2] * v[2] + v[3] * v[3];
#pragma unroll
  for (int m = 1; m < 32; m <<= 1) ss += __shfl_xor(ss, m);
  const float inv = 1.f / fmaxf(sqrtf(ss), 1e-12f);
  v *= inv;
  *(vf4*)&out[(size_t)row * 128 + o0] = v;
}

extern "C" void kernel_launch(void* const* d_in, const int* in_sizes, int n_in,
                              void* d_out, int out_size, void* d_ws, size_t ws_size,
                              hipStream_t stream) {
  const float* x = (const float*)d_in[0];
  const float* left0 = (const float*)d_in[1];
  const float* left_rest = (const float*)d_in[2];
  const float* center = (const float*)d_in[3];
  const float* right_rest = (const float*)d_in[4];
  const float* right_last = (const float*)d_in[5];
  float* out = (float*)d_out;

  char* wsb = (char*)d_ws;
  unsigned short* Wl = (unsigned short*)wsb;                         // 8.37 MB
  unsigned short* Wr = Wl + (size_t)NS * SITE_F;                     // 8.37 MB
  float* envL = (float*)(Wr + (size_t)NS * SITE_F);                  // 1 MB
  float* envR = envL + (size_t)BBATCH * 64;                          // 1 MB
  unsigned short* Rb16 = (unsigned short*)(envR + (size_t)BBATCH * 64);  // 0.5 MB
  unsigned short* Cf = Rb16 + (size_t)BBATCH * 64;                   // 1 MB
  float* Pp = (float*)(Cf + (size_t)OO * 8 * 64 * 8);                // 2 MB

  hipLaunchKernelGGL(prep, dim3(NS, 2), dim3(256), 0, stream,
                     left_rest, right_rest, Wl, Wr);
  hipLaunchKernelGGL(prep2, dim3(OO), dim3(256), 0, stream, center, Cf);
  hipLaunchKernelGGL(sweep, dim3(512), dim3(64), 0, stream,
                     x, left0, right_last, Wl, Wr, envL, envR, Rb16);
  hipLaunchKernelGGL(centerk2, dim3(BBATCH / 16), dim3(256), 0, stream,
                     envL, Rb16, Cf, Pp);
  hipLaunchKernelGGL(combinek2, dim3(BBATCH / 8), dim3(256), 0, stream, Pp, out);
}

// Round 19
// 408.678 us; speedup vs baseline: 1.0680x; 1.0149x over previous
//
#include <hip/hip_runtime.h>

typedef float vf4 __attribute__((ext_vector_type(4)));
typedef int vi4 __attribute__((ext_vector_type(4)));
typedef int vi2 __attribute__((ext_vector_type(2)));
typedef short short8 __attribute__((ext_vector_type(8)));
typedef unsigned short ushort8 __attribute__((ext_vector_type(8)));

#define LL 1024
#define OO 128
#define BBATCH 4096
#define NS 511          // sites per sweep
#define SITE_F 8192     // elements per site tensor (64*2*64)
#define XROWS 504       // sites with x staged in LDS (rest in tail)

// ---- async global->LDS ----
__device__ __forceinline__ void gld_lds16(const float* g, float* l) {
  __builtin_amdgcn_global_load_lds(
      (const __attribute__((address_space(1))) unsigned int*)g,
      (__attribute__((address_space(3))) unsigned int*)l, 16, 0, 0);
}
__device__ __forceinline__ void gld_lds4(const float* g, float* l) {
  __builtin_amdgcn_global_load_lds(
      (const __attribute__((address_space(1))) unsigned int*)g,
      (__attribute__((address_space(3))) unsigned int*)l, 4, 0, 0);
}

__device__ __forceinline__ unsigned short f2bf(float v) {
  const unsigned uu = __builtin_bit_cast(unsigned, v);
  return (unsigned short)((uu + 0x7FFFu + ((uu >> 16) & 1u)) >> 16);  // RNE
}

// ---- one-shot: build bf16 16x16x32-frag-major N = A - I (verbatim R15) ----
__global__ __launch_bounds__(256) void prep(const float* __restrict__ lsrc,
                                            const float* __restrict__ rsrc,
                                            unsigned short* __restrict__ Wl,
                                            unsigned short* __restrict__ Wr) {
  __shared__ float S[SITE_F];
  const int site = blockIdx.x;
  const int dir = blockIdx.y;
  const int tid = threadIdx.x;
  const float* src = (dir ? rsrc : lsrc) + (size_t)site * SITE_F;
  unsigned short* dst = dir ? (Wr + (size_t)(NS - 1 - site) * SITE_F)
                            : (Wl + (size_t)site * SITE_F);
#pragma unroll
  for (int m = 0; m < 8; m++)
    *(vf4*)&S[(m * 256 + tid) * 4] = *(const vf4*)&src[(m * 256 + tid) * 4];
  __syncthreads();
#pragma unroll
  for (int q = 0; q < 4; q++) {
    const int slot = q * 256 + tid;           // 0..1023 = f*64 + lane
    const int lane = slot & 63, f = slot >> 6;
    const int mt = f >> 2, s = f & 3;
    const int g = lane >> 4, c = lane & 15;
    const int m = 16 * mt + c;
    ushort8 t;
#pragma unroll
    for (int j = 0; j < 8; j++) {
      const int k = 32 * s + 8 * g + j;
      float v;
      if (dir == 0) {
        const int l = k >> 1, p = k & 1;
        v = S[l * 128 + p * 64 + m] - ((m == l) ? 1.f : 0.f);
      } else {
        const int r = k >> 1, p = k & 1;
        v = S[m * 128 + p * 64 + r] - ((m == r) ? 1.f : 0.f);
      }
      t[j] = f2bf(v);
    }
    *(ushort8*)&dst[(size_t)slot * 8] = t;
  }
}

// ---- one-shot: pack center C[l][r][o] into per-o A-frags (verbatim) ----
__global__ __launch_bounds__(256) void prep2(const float* __restrict__ center,
                                             unsigned short* __restrict__ Cf) {
  __shared__ float S[4096];
  const int o = blockIdx.x;
  const int tid = threadIdx.x;
#pragma unroll
  for (int k = 0; k < 16; k++) {
    const int idx = k * 256 + tid;
    S[idx] = center[(size_t)idx * 128 + o];
  }
  __syncthreads();
#pragma unroll
  for (int q = 0; q < 2; q++) {
    const int slot = q * 256 + tid;
    const int lane = slot & 63, f = slot >> 6;
    const int mt = f >> 1, s = f & 1;
    const int g = lane >> 4, c = lane & 15;
    const int l = 16 * mt + c;
    ushort8 t;
#pragma unroll
    for (int j = 0; j < 8; j++) {
      const int r = 32 * s + 8 * g + j;
      t[j] = f2bf(S[l * 64 + r]);
    }
    *(ushort8*)&Cf[(size_t)((o * 8 + f) * 64 + lane) * 8] = t;
  }
}

// ---- stage one 2-site group (32KB) with 128 threads (16 counted ops) ----
#define STAGE_GROUP(G, SL)                                                     \
  {                                                                            \
    _Pragma("unroll")                                                          \
    for (int s2 = 0; s2 < 2; s2++) {                                           \
      int st_ = (G) * 2 + s2;                                                  \
      if (st_ > NS - 1) st_ = NS - 1;                                          \
      const float* src_ = Wf + (size_t)st_ * 4096;                             \
      float* d_ = &ring[SL][s2][0];                                            \
      _Pragma("unroll")                                                        \
      for (int q = 0; q < 8; q++)                                              \
        gld_lds16(src_ + q * 512 + tid * 4, d_ + q * 512 + tid * 4);           \
    }                                                                          \
  }

// ---- per-site body: trig from XV, W frags from resident LDS ----
#define BODY(I, SL, S2, XV, RS)                                                \
  {                                                                            \
    const float qrev = 0.25f * (XV); /* cos(pi/2 x)=cos(2pi*(x/4)) */          \
    float c_, s_;                                                              \
    asm("v_cos_f32 %0, %1" : "=v"(c_) : "v"(qrev));                            \
    asm("v_sin_f32 %0, %1" : "=v"(s_) : "v"(qrev));                            \
    const float CS = c_, SN = s_;                                              \
    const float* rb = &ring[SL][S2][0];                                        \
    vf4 FC[16];                                                                \
    _Pragma("unroll")                                                          \
    for (int q = 0; q < 16; q++)                                               \
      FC[q] = *(const vf4*)&rb[(q * 64 + lane) * 4];                           \
    short8 e2[4];                                                              \
    _Pragma("unroll")                                                          \
    for (int s = 0; s < 4; s++) {                                              \
      int pk[4];                                                               \
      _Pragma("unroll")                                                        \
      for (int t = 0; t < 4; t++) {                                            \
        const float f0 = u[s][t] * CS, f1 = u[s][t] * SN;                      \
        int p;                                                                 \
        asm("v_cvt_pk_bf16_f32 %0, %1, %2" : "=v"(p) : "v"(f0), "v"(f1));      \
        pk[t] = p;                                                             \
      }                                                                        \
      e2[s] = __builtin_bit_cast(short8, (vi4){pk[0], pk[1], pk[2], pk[3]});   \
    }                                                                          \
    const float keff = CS + SN;                                                \
    vf4 accA[4], accB[4];                                                      \
    _Pragma("unroll")                                                          \
    for (int mt = 0; mt < 4; mt++) {                                           \
      vf4 z;                                                                   \
      z[0] = keff * u[mt][0]; z[1] = keff * u[mt][1];                          \
      z[2] = keff * u[mt][2]; z[3] = keff * u[mt][3];                          \
      accA[mt] = z;                                                            \
      accB[mt] = (vf4){0.f, 0.f, 0.f, 0.f};                                    \
    }                                                                          \
    _Pragma("unroll")                                                          \
    for (int mt = 0; mt < 4; mt++) {                                           \
      accA[mt] = __builtin_amdgcn_mfma_f32_16x16x32_bf16(                      \
          __builtin_bit_cast(short8, FC[mt * 4 + 0]), e2[0], accA[mt], 0,0,0); \
      accA[mt] = __builtin_amdgcn_mfma_f32_16x16x32_bf16(                      \
          __builtin_bit_cast(short8, FC[mt * 4 + 1]), e2[1], accA[mt], 0,0,0); \
      accB[mt] = __builtin_amdgcn_mfma_f32_16x16x32_bf16(                      \
          __builtin_bit_cast(short8, FC[mt * 4 + 2]), e2[2], accB[mt], 0,0,0); \
      accB[mt] = __builtin_amdgcn_mfma_f32_16x16x32_bf16(                      \
          __builtin_bit_cast(short8, FC[mt * 4 + 3]), e2[3], accB[mt], 0,0,0); \
    }                                                                          \
    _Pragma("unroll")                                                          \
    for (int mt = 0; mt < 4; mt++) u[mt] = accA[mt] + accB[mt];                \
    if (RS) { /* exact pow2 rescale, keeps fp32 in range */                    \
      float nss = 0.f;                                                         \
      _Pragma("unroll")                                                        \
      for (int mt = 0; mt < 4; mt++)                                           \
        _Pragma("unroll")                                                      \
        for (int r = 0; r < 4; r++) nss += u[mt][r] * u[mt][r];                \
      nss += __shfl_xor(nss, 16);                                              \
      nss += __shfl_xor(nss, 32);                                              \
      const int eb = (__float_as_int(nss) >> 23) & 0xFF;                       \
      const float alpha = __int_as_float((127 - ((eb - 127) >> 1)) << 23);     \
      _Pragma("unroll")                                                        \
      for (int mt = 0; mt < 4; mt++)                                           \
        _Pragma("unroll")                                                      \
        for (int r = 0; r < 4; r++) u[mt][r] *= alpha;                         \
    }                                                                          \
  }

#define WAITBAR(VCS)                                                           \
  asm volatile("s_waitcnt vmcnt(" VCS ")" ::: "memory");                       \
  __builtin_amdgcn_sched_barrier(0);                                           \
  __builtin_amdgcn_s_barrier();

// ---- sweep: 256 blocks x 2 waves (16-sample chains each) ----
// ring-3 of 2-site groups + counted vmcnt(16) + RAW s_barrier (no drain);
// x pre-staged in LDS (no compiler VMEM in steady-state loop).
// XCD swizzle: XCDs 0-3 -> dir 0, XCDs 4-7 -> dir 1.
__global__ __launch_bounds__(128, 1) void sweep(const float* __restrict__ x,
                                                const float* __restrict__ left0,
                                                const float* __restrict__ right_last,
                                                const unsigned short* __restrict__ Wl,
                                                const unsigned short* __restrict__ Wr,
                                                float* __restrict__ envL,
                                                float* __restrict__ envR,
                                                unsigned short* __restrict__ Rb16) {
  __shared__ float ring[3][2][4096];   // 96 KB: 3 slots x 2 sites x 16KB
  __shared__ float xls[XROWS][32];     // 63 KB: x for sites 0..503
  const int bid = blockIdx.x;          // 0..255
  const int xcd = bid & 7;
  const int dir = xcd >> 2;
  const int slot = (xcd & 3) * 32 + (bid >> 3);   // 0..127 within dir
  const int tid = threadIdx.x;
  const int wave = tid >> 6;
  const int lane = tid & 63;
  const int g_ = lane >> 4, c = lane & 15;
  const int b0 = slot * 32;
  const int b = b0 + wave * 16 + c;
  const int widx = wave * 16 + c;
  const float* xrow = x + (size_t)b * LL;

  const float* Wf = (const float*)(dir ? Wr : Wl);

  // init env (fp32, exact normalize; compiler loads, pre-loop)
  vf4 u[4];
  {
    const float x0 = xrow[dir ? (LL - 1) : 0];
    const float qrev = 0.25f * x0;
    float cs, sn;
    asm("v_cos_f32 %0, %1" : "=v"(cs) : "v"(qrev));
    asm("v_sin_f32 %0, %1" : "=v"(sn) : "v"(qrev));
#pragma unroll
    for (int mt = 0; mt < 4; mt++)
#pragma unroll
      for (int r = 0; r < 4; r++) {
        const int n = 16 * mt + 4 * g_ + r;
        const float w0 = dir ? right_last[n * 2] : left0[n];
        const float w1 = dir ? right_last[n * 2 + 1] : left0[64 + n];
        u[mt][r] = cs * w0 + sn * w1;
      }
    float ss = 0.f;
#pragma unroll
    for (int mt = 0; mt < 4; mt++)
#pragma unroll
      for (int r = 0; r < 4; r++) ss += u[mt][r] * u[mt][r];
    ss += __shfl_xor(ss, 16);
    ss += __shfl_xor(ss, 32);
    const float a0 = 1.f / (sqrtf(ss) + 1e-8f);
#pragma unroll
    for (int mt = 0; mt < 4; mt++)
#pragma unroll
      for (int r = 0; r < 4; r++) u[mt][r] *= a0;
  }

  // ---- prologue staging: x rows (126 ops) + groups 0,1 (32 ops) ----
  {
    float* xd = &xls[0][0];
    for (int op = 0; op < (XROWS * 32) / 128; op++) {
      const int e = op * 128 + tid;        // 0..16127
      const int I = e >> 5, s = e & 31;
      const int t = dir ? (1022 - I) : (1 + I);
      gld_lds4(x + (size_t)(b0 + s) * LL + t, xd + e);
    }
  }
  STAGE_GROUP(0, 0)
  STAGE_GROUP(1, 1)

  // ---- main loop: groups 0..251 (sites 0..503), x from LDS ----
  int sl = 0;
  for (int g = 0; g < 252; g++) {
    WAITBAR("16")                      // retires group g (x+grp0 at g=0)
    const float xv0 = xls[2 * g][widx];
    const float xv1 = xls[2 * g + 1][widx];
    BODY(2 * g, sl, 0, xv0, 0)
    BODY(2 * g + 1, sl, 1, xv1, (g & 3) == 3)
    const int sl2 = (sl == 0) ? 2 : (sl - 1);   // (g+2)%3
    STAGE_GROUP(g + 2, sl2)
    sl = (sl == 2) ? 0 : (sl + 1);
  }
  // ---- tail groups 252..255 (sites 504..510), x via compiler loads ----
  {
    WAITBAR("16")                      // group 252 ready (sl = 252%3 = 0)
    const float xa = xrow[dir ? (1022 - 504) : (1 + 504)];
    const float xb = xrow[dir ? (1022 - 505) : (1 + 505)];
    BODY(504, 0, 0, xa, 0)
    BODY(505, 0, 1, xb, 0)
    STAGE_GROUP(254, 2)
    WAITBAR("16")                      // group 253 (slot 1)
    const float xc = xrow[dir ? (1022 - 506) : (1 + 506)];
    const float xd = xrow[dir ? (1022 - 507) : (1 + 507)];
    BODY(506, 1, 0, xc, 0)
    BODY(507, 1, 1, xd, 0)
    STAGE_GROUP(255, 0)
    WAITBAR("16")                      // group 254 (slot 2)
    const float xe = xrow[dir ? (1022 - 508) : (1 + 508)];
    const float xf = xrow[dir ? (1022 - 509) : (1 + 509)];
    BODY(508, 2, 0, xe, 0)
    BODY(509, 2, 1, xf, 0)
    WAITBAR("0")                       // group 255 (slot 0)
    const float xg = xrow[dir ? (1022 - 510) : (1 + 510)];
    BODY(510, 0, 0, xg, 0)
  }

  // final exact normalize + store (f32 env + bf16 copy for centerk2)
  float nss = 0.f;
#pragma unroll
  for (int mt = 0; mt < 4; mt++)
#pragma unroll
    for (int r = 0; r < 4; r++) nss += u[mt][r] * u[mt][r];
  nss += __shfl_xor(nss, 16);
  nss += __shfl_xor(nss, 32);
  const float alpha = 1.f / (sqrtf(nss) + 1e-8f);

  float* eo = (dir ? envR : envL) + (size_t)b * 64;
#pragma unroll
  for (int mt = 0; mt < 4; mt++) {
    vf4 v;
#pragma unroll
    for (int r = 0; r < 4; r++) v[r] = u[mt][r] * alpha;
    *(vf4*)&eo[16 * mt + 4 * g_] = v;
    if (dir) {
      int p01, p23;
      asm("v_cvt_pk_bf16_f32 %0, %1, %2" : "=v"(p01) : "v"(v[0]), "v"(v[1]));
      asm("v_cvt_pk_bf16_f32 %0, %1, %2" : "=v"(p23) : "v"(v[2]), "v"(v[3]));
      *(vi2*)&Rb16[(size_t)b * 64 + 16 * mt + 4 * g_] = (vi2){p01, p23};
    }
  }
}

// ---- center contraction via MFMA (verbatim R15) ----
__global__ __launch_bounds__(256) void centerk2(const float* __restrict__ envL,
                                                const unsigned short* __restrict__ Rb16,
                                                const unsigned short* __restrict__ Cf,
                                                float* __restrict__ Pp) {
  const int b0 = blockIdx.x * 16;
  const int tid = threadIdx.x;
  const int wave = tid >> 6;
  const int lane = tid & 63;
  const int g = lane >> 4, c = lane & 15;

  short8 rf[2];
#pragma unroll
  for (int s = 0; s < 2; s++)
    rf[s] = __builtin_bit_cast(short8,
        *(const ushort8*)&Rb16[(size_t)(b0 + c) * 64 + 32 * s + 8 * g]);

  vf4 Lv[4];
#pragma unroll
  for (int mt = 0; mt < 4; mt++)
    Lv[mt] = *(const vf4*)&envL[(size_t)(b0 + c) * 64 + 16 * mt + 4 * g];

  for (int oi = 0; oi < 32; oi++) {
    const int o = wave * 32 + oi;
    const unsigned short* cb = Cf + (size_t)(o * 8) * 64 * 8;
    vf4 acc[4];
#pragma unroll
    for (int mt = 0; mt < 4; mt++) {
      const short8 a0 = __builtin_bit_cast(short8,
          *(const ushort8*)&cb[(size_t)((mt * 2 + 0) * 64 + lane) * 8]);
      const short8 a1 = __builtin_bit_cast(short8,
          *(const ushort8*)&cb[(size_t)((mt * 2 + 1) * 64 + lane) * 8]);
      vf4 z = {0.f, 0.f, 0.f, 0.f};
      z = __builtin_amdgcn_mfma_f32_16x16x32_bf16(a0, rf[0], z, 0, 0, 0);
      z = __builtin_amdgcn_mfma_f32_16x16x32_bf16(a1, rf[1], z, 0, 0, 0);
      acc[mt] = z;
    }
    float ps = 0.f;
#pragma unroll
    for (int mt = 0; mt < 4; mt++)
#pragma unroll
      for (int r = 0; r < 4; r++) ps += Lv[mt][r] * acc[mt][r];
    ps += __shfl_xor(ps, 16);
    ps += __shfl_xor(ps, 32);
    if (g == 0) Pp[(size_t)(b0 + c) * 128 + o] = ps;
  }
}

// ---- row-normalize Pp -> out ----
__global__ __launch_bounds__(256) void combinek2(const float* __restrict__ P,
                                                 float* __restrict__ out) {
  const int row = blockIdx.x * 8 + (threadIdx.x >> 5);
  const int o0 = (threadIdx.x & 31) * 4;
  vf4 v = *(const vf4*)&P[(size_t)row * 128 + o0];
  float ss = v[0] * v[0] + v[1] * v[1] + v[2] * v[2] + v[3] * v[3];
#pragma unroll
  for (int m = 1; m < 32; m <<= 1) ss += __shfl_xor(ss, m);
  const float inv = 1.f / fmaxf(sqrtf(ss), 1e-12f);
  v *= inv;
  *(vf4*)&out[(size_t)row * 128 + o0] = v;
}

extern "C" void kernel_launch(void* const* d_in, const int* in_sizes, int n_in,
                              void* d_out, int out_size, void* d_ws, size_t ws_size,
                              hipStream_t stream) {
  const float* x = (const float*)d_in[0];
  const float* left0 = (const float*)d_in[1];
  const float* left_rest = (const float*)d_in[2];
  const float* center = (const float*)d_in[3];
  const float* right_rest = (const float*)d_in[4];
  const float* right_last = (const float*)d_in[5];
  float* out = (float*)d_out;

  char* wsb = (char*)d_ws;
  unsigned short* Wl = (unsigned short*)wsb;                         // 8.37 MB
  unsigned short* Wr = Wl + (size_t)NS * SITE_F;                     // 8.37 MB
  float* envL = (float*)(Wr + (size_t)NS * SITE_F);                  // 1 MB
  float* envR = envL + (size_t)BBATCH * 64;                          // 1 MB
  unsigned short* Rb16 = (unsigned short*)(envR + (size_t)BBATCH * 64);  // 0.5 MB
  unsigned short* Cf = Rb16 + (size_t)BBATCH * 64;                   // 1 MB
  float* Pp = (float*)(Cf + (size_t)OO * 8 * 64 * 8);                // 2 MB

  hipLaunchKernelGGL(prep, dim3(NS, 2), dim3(256), 0, stream,
                     left_rest, right_rest, Wl, Wr);
  hipLaunchKernelGGL(prep2, dim3(OO), dim3(256), 0, stream, center, Cf);
  hipLaunchKernelGGL(sweep, dim3(256), dim3(128), 0, stream,
                     x, left0, right_last, Wl, Wr, envL, envR, Rb16);
  hipLaunchKernelGGL(centerk2, dim3(BBATCH / 16), dim3(256), 0, stream,
                     envL, Rb16, Cf, Pp);
  hipLaunchKernelGGL(combinek2, dim3(BBATCH / 8), dim3(256), 0, stream, Pp, out);
}

// Round 20
// 320.029 us; speedup vs baseline: 1.3639x; 1.2770x over previous
//
#include <hip/hip_runtime.h>

typedef float vf4 __attribute__((ext_vector_type(4)));
typedef int vi4 __attribute__((ext_vector_type(4)));
typedef int vi2 __attribute__((ext_vector_type(2)));
typedef short short8 __attribute__((ext_vector_type(8)));
typedef unsigned short ushort8 __attribute__((ext_vector_type(8)));

#define LL 1024
#define OO 128
#define BBATCH 4096
#define NS 511          // sites per sweep
#define SITE_F 8192     // elements per site tensor (64*2*64)

// ---- async global->LDS ----
__device__ __forceinline__ void gld_lds16(const float* g, float* l) {
  __builtin_amdgcn_global_load_lds(
      (const __attribute__((address_space(1))) unsigned int*)g,
      (__attribute__((address_space(3))) unsigned int*)l, 16, 0, 0);
}

__device__ __forceinline__ unsigned short f2bf(float v) {
  const unsigned uu = __builtin_bit_cast(unsigned, v);
  return (unsigned short)((uu + 0x7FFFu + ((uu >> 16) & 1u)) >> 16);  // RNE
}

// ---- one-shot: build bf16 16x16x32-frag-major N = A - I for both sweeps ----
// layout: W[site][f][lane][j] bf16, f = mt*4+s (mt=M-tile 0..3, s=K-step 0..3)
// A elem: m = 16*mt + (lane&15); k = 32*s + 8*(lane>>4) + j  (k = 2*env_in + p)
// right buffer is site-reversed so the sweep always walks ascending.
__global__ __launch_bounds__(256) void prep(const float* __restrict__ lsrc,
                                            const float* __restrict__ rsrc,
                                            unsigned short* __restrict__ Wl,
                                            unsigned short* __restrict__ Wr) {
  __shared__ float S[SITE_F];
  const int site = blockIdx.x;
  const int dir = blockIdx.y;
  const int tid = threadIdx.x;
  const float* src = (dir ? rsrc : lsrc) + (size_t)site * SITE_F;
  unsigned short* dst = dir ? (Wr + (size_t)(NS - 1 - site) * SITE_F)
                            : (Wl + (size_t)site * SITE_F);
#pragma unroll
  for (int m = 0; m < 8; m++)
    *(vf4*)&S[(m * 256 + tid) * 4] = *(const vf4*)&src[(m * 256 + tid) * 4];
  __syncthreads();
#pragma unroll
  for (int q = 0; q < 4; q++) {
    const int slot = q * 256 + tid;           // 0..1023 = f*64 + lane
    const int lane = slot & 63, f = slot >> 6;
    const int mt = f >> 2, s = f & 3;
    const int g = lane >> 4, c = lane & 15;
    const int m = 16 * mt + c;
    ushort8 t;
#pragma unroll
    for (int j = 0; j < 8; j++) {
      const int k = 32 * s + 8 * g + j;
      float v;
      if (dir == 0) {
        const int l = k >> 1, p = k & 1;
        v = S[l * 128 + p * 64 + m] - ((m == l) ? 1.f : 0.f);
      } else {
        const int r = k >> 1, p = k & 1;
        v = S[m * 128 + p * 64 + r] - ((m == r) ? 1.f : 0.f);
      }
      t[j] = f2bf(v);
    }
    *(ushort8*)&dst[(size_t)slot * 8] = t;
  }
}

// ---- one-shot: pack center C[l][r][o] into per-o A-frags (bf16) ----
__global__ __launch_bounds__(256) void prep2(const float* __restrict__ center,
                                             unsigned short* __restrict__ Cf) {
  __shared__ float S[4096];        // C[:,:,o] slab, [l*64+r]
  const int o = blockIdx.x;
  const int tid = threadIdx.x;
#pragma unroll
  for (int k = 0; k < 16; k++) {
    const int idx = k * 256 + tid;
    S[idx] = center[(size_t)idx * 128 + o];
  }
  __syncthreads();
#pragma unroll
  for (int q = 0; q < 2; q++) {
    const int slot = q * 256 + tid;           // 0..511 = f*64 + lane
    const int lane = slot & 63, f = slot >> 6;
    const int mt = f >> 1, s = f & 1;
    const int g = lane >> 4, c = lane & 15;
    const int l = 16 * mt + c;
    ushort8 t;
#pragma unroll
    for (int j = 0; j < 8; j++) {
      const int r = 32 * s + 8 * g + j;
      t[j] = f2bf(S[l * 64 + r]);
    }
    *(ushort8*)&Cf[(size_t)((o * 8 + f) * 64 + lane) * 8] = t;
  }
}

// ---- stage one 4-site group (64KB) with 128 threads ----
#define STAGE_GROUP(G, BUF)                                                    \
  {                                                                            \
    _Pragma("unroll")                                                          \
    for (int s4 = 0; s4 < 4; s4++) {                                           \
      int st_ = (G) * 4 + s4;                                                  \
      if (st_ > NS - 1) st_ = NS - 1;                                          \
      const float* Ws_ = Wf + (size_t)st_ * 4096;                              \
      float* d_ = &ring[BUF][s4][0];                                           \
      _Pragma("unroll")                                                        \
      for (int q = 0; q < 8; q++)                                              \
        gld_lds16(Ws_ + q * 512 + tid * 4, d_ + q * 512 + tid * 4);            \
    }                                                                          \
  }

#define LOAD_FC(FC, RB)                                                        \
  {                                                                            \
    const float* rb_ = (RB);                                                   \
    _Pragma("unroll")                                                          \
    for (int q = 0; q < 16; q++)                                               \
      FC[q] = *(const vf4*)&rb_[(q * 64 + lane) * 4];                          \
  }

// ---- per-site body: compute with FCc; prefetch FCn <- RBN when PF ----
#define BODYP(I, FCc, FCn, RBN, PF)                                            \
  {                                                                            \
    if (PF) {                                                                  \
      LOAD_FC(FCn, RBN)                                                        \
      __builtin_amdgcn_sched_barrier(0);                                       \
    }                                                                          \
    const int nI = (I) + 1;                                                    \
    float xn = 0.f;                                                            \
    if (nI <= NS - 1) xn = xrow[dir ? (1022 - nI) : (1 + nI)];                 \
    short8 e2[4];                                                              \
    _Pragma("unroll")                                                          \
    for (int s = 0; s < 4; s++) {                                              \
      int pk[4];                                                               \
      _Pragma("unroll")                                                        \
      for (int t = 0; t < 4; t++) {                                            \
        const float f0 = u[s][t] * CS, f1 = u[s][t] * SN;                      \
        int p;                                                                 \
        asm("v_cvt_pk_bf16_f32 %0, %1, %2" : "=v"(p) : "v"(f0), "v"(f1));      \
        pk[t] = p;                                                             \
      }                                                                        \
      e2[s] = __builtin_bit_cast(short8, (vi4){pk[0], pk[1], pk[2], pk[3]});   \
    }                                                                          \
    const float keff = CS + SN;                                                \
    vf4 accA[4], accB[4];                                                      \
    _Pragma("unroll")                                                          \
    for (int mt = 0; mt < 4; mt++) {                                           \
      vf4 z;                                                                   \
      z[0] = keff * u[mt][0]; z[1] = keff * u[mt][1];                          \
      z[2] = keff * u[mt][2]; z[3] = keff * u[mt][3];                          \
      accA[mt] = z;                                                            \
      accB[mt] = (vf4){0.f, 0.f, 0.f, 0.f};                                    \
    }                                                                          \
    _Pragma("unroll")                                                          \
    for (int mt = 0; mt < 4; mt++) {                                           \
      accA[mt] = __builtin_amdgcn_mfma_f32_16x16x32_bf16(                      \
          __builtin_bit_cast(short8, FCc[mt * 4 + 0]), e2[0], accA[mt], 0,0,0);\
      accA[mt] = __builtin_amdgcn_mfma_f32_16x16x32_bf16(                      \
          __builtin_bit_cast(short8, FCc[mt * 4 + 1]), e2[1], accA[mt], 0,0,0);\
      accB[mt] = __builtin_amdgcn_mfma_f32_16x16x32_bf16(                      \
          __builtin_bit_cast(short8, FCc[mt * 4 + 2]), e2[2], accB[mt], 0,0,0);\
      accB[mt] = __builtin_amdgcn_mfma_f32_16x16x32_bf16(                      \
          __builtin_bit_cast(short8, FCc[mt * 4 + 3]), e2[3], accB[mt], 0,0,0);\
    }                                                                          \
    _Pragma("unroll")                                                          \
    for (int mt = 0; mt < 4; mt++) u[mt] = accA[mt] + accB[mt];                \
    if (nI <= NS - 1) {                                                        \
      const float qrev = 0.25f * xn; /* cos(pi/2 x)=cos(2pi*(x/4)) */          \
      float c_, s_;                                                            \
      asm("v_cos_f32 %0, %1" : "=v"(c_) : "v"(qrev));                          \
      asm("v_sin_f32 %0, %1" : "=v"(s_) : "v"(qrev));                          \
      CS = c_;                                                                 \
      SN = s_;                                                                 \
    }                                                                          \
    if (((I) & 7) == 7) { /* exact pow2 rescale */                             \
      float nss = 0.f;                                                         \
      _Pragma("unroll")                                                        \
      for (int mt = 0; mt < 4; mt++)                                           \
        _Pragma("unroll")                                                      \
        for (int r = 0; r < 4; r++) nss += u[mt][r] * u[mt][r];                \
      nss += __shfl_xor(nss, 16);                                              \
      nss += __shfl_xor(nss, 32);                                              \
      const int eb = (__float_as_int(nss) >> 23) & 0xFF;                       \
      const float alpha = __int_as_float((127 - ((eb - 127) >> 1)) << 23);     \
      _Pragma("unroll")                                                        \
      for (int mt = 0; mt < 4; mt++)                                           \
        _Pragma("unroll")                                                      \
        for (int r = 0; r < 4; r++) u[mt][r] *= alpha;                         \
    }                                                                          \
  }

// ---- sweep: 256 blocks x 2 waves (16-sample chains); group dbuf + FC dbuf --
__global__ __launch_bounds__(128, 1) void sweep(const float* __restrict__ x,
                                                const float* __restrict__ left0,
                                                const float* __restrict__ right_last,
                                                const unsigned short* __restrict__ Wl,
                                                const unsigned short* __restrict__ Wr,
                                                float* __restrict__ envL,
                                                float* __restrict__ envR,
                                                unsigned short* __restrict__ Lb16,
                                                unsigned short* __restrict__ Rb16) {
  __shared__ float ring[2][4][4096];   // 2 groups x 4 sites x 16KB = 128KB
  const int bid = blockIdx.x;          // 0..255
  const int xcd = bid & 7;
  const int dir = xcd >> 2;
  const int slot = (xcd & 3) * 32 + (bid >> 3);   // 0..127 within dir
  const int tid = threadIdx.x;
  const int wave = tid >> 6;
  const int lane = tid & 63;
  const int g_ = lane >> 4, c = lane & 15;
  const int b = (slot * 2 + wave) * 16 + c;
  const float* xrow = x + (size_t)b * LL;

  const float* Wf = (const float*)(dir ? Wr : Wl);

  // init env (fp32, exact normalize)
  vf4 u[4];
  {
    const float x0 = xrow[dir ? (LL - 1) : 0];
    const float qrev = 0.25f * x0;
    float cs, sn;
    asm("v_cos_f32 %0, %1" : "=v"(cs) : "v"(qrev));
    asm("v_sin_f32 %0, %1" : "=v"(sn) : "v"(qrev));
#pragma unroll
    for (int mt = 0; mt < 4; mt++)
#pragma unroll
      for (int r = 0; r < 4; r++) {
        const int n = 16 * mt + 4 * g_ + r;
        const float w0 = dir ? right_last[n * 2] : left0[n];
        const float w1 = dir ? right_last[n * 2 + 1] : left0[64 + n];
        u[mt][r] = cs * w0 + sn * w1;
      }
    float ss = 0.f;
#pragma unroll
    for (int mt = 0; mt < 4; mt++)
#pragma unroll
      for (int r = 0; r < 4; r++) ss += u[mt][r] * u[mt][r];
    ss += __shfl_xor(ss, 16);
    ss += __shfl_xor(ss, 32);
    const float a0 = 1.f / (sqrtf(ss) + 1e-8f);
#pragma unroll
    for (int mt = 0; mt < 4; mt++)
#pragma unroll
      for (int r = 0; r < 4; r++) u[mt][r] *= a0;
  }

  float CS, SN;
  {
    const float q0 = 0.25f * xrow[dir ? 1022 : 1];
    asm("v_cos_f32 %0, %1" : "=v"(CS) : "v"(q0));
    asm("v_sin_f32 %0, %1" : "=v"(SN) : "v"(q0));
  }

  STAGE_GROUP(0, 0)
  __syncthreads();

  vf4 fX[16], fY[16];
  for (int g = 0; g < 127; g++) {
    const int buf = g & 1;
    LOAD_FC(fX, &ring[buf][0][0])
    STAGE_GROUP(g + 1, buf ^ 1)     // prefetch next group while computing
    const int i0 = g * 4;
    BODYP(i0 + 0, fX, fY, &ring[buf][1][0], 1)
    BODYP(i0 + 1, fY, fX, &ring[buf][2][0], 1)
    BODYP(i0 + 2, fX, fY, &ring[buf][3][0], 1)
    BODYP(i0 + 3, fY, fX, &ring[buf][0][0], 0)
    __syncthreads();                // drain stage(g+1); buf reusable
  }
  // tail group 127: sites 508..510 in buf 1
  LOAD_FC(fX, &ring[1][0][0])
  BODYP(508, fX, fY, &ring[1][1][0], 1)
  BODYP(509, fY, fX, &ring[1][2][0], 1)
  BODYP(510, fX, fY, &ring[1][3][0], 0)

  // final exact normalize + store (f32 + bf16 fragment-ready copy)
  float nss = 0.f;
#pragma unroll
  for (int mt = 0; mt < 4; mt++)
#pragma unroll
    for (int r = 0; r < 4; r++) nss += u[mt][r] * u[mt][r];
  nss += __shfl_xor(nss, 16);
  nss += __shfl_xor(nss, 32);
  const float alpha = 1.f / (sqrtf(nss) + 1e-8f);

  float* eo = (dir ? envR : envL) + (size_t)b * 64;
  unsigned short* eo16 = (dir ? Rb16 : Lb16) + (size_t)b * 64;
#pragma unroll
  for (int mt = 0; mt < 4; mt++) {
    vf4 v;
#pragma unroll
    for (int r = 0; r < 4; r++) v[r] = u[mt][r] * alpha;
    *(vf4*)&eo[16 * mt + 4 * g_] = v;
    int p01, p23;
    asm("v_cvt_pk_bf16_f32 %0, %1, %2" : "=v"(p01) : "v"(v[0]), "v"(v[1]));
    asm("v_cvt_pk_bf16_f32 %0, %1, %2" : "=v"(p23) : "v"(v[2]), "v"(v[3]));
    *(vi2*)&eo16[16 * mt + 4 * g_] = (vi2){p01, p23};
  }
}

// ---- center contraction via MFMA: out[b,o] = L[b,:]·(C_o·R[b,:]^T) ----
// 256 blocks (16 b each) x 4 waves (32 o each) = 4 waves/CU.
__global__ __launch_bounds__(256) void centerk2(const float* __restrict__ envL,
                                                const unsigned short* __restrict__ Rb16,
                                                const unsigned short* __restrict__ Cf,
                                                float* __restrict__ Pp) {
  const int b0 = blockIdx.x * 16;
  const int tid = threadIdx.x;
  const int wave = tid >> 6;
  const int lane = tid & 63;
  const int g = lane >> 4, c = lane & 15;

  // B-frags: R[b0+c][r], r = 32s + 8g + j  (2 frags, loaded once)
  short8 rf[2];
#pragma unroll
  for (int s = 0; s < 2; s++)
    rf[s] = __builtin_bit_cast(short8,
        *(const ushort8*)&Rb16[(size_t)(b0 + c) * 64 + 32 * s + 8 * g]);

  // L values: L[b0+c][16mt + 4g + r] (4 vf4, loaded once)
  vf4 Lv[4];
#pragma unroll
  for (int mt = 0; mt < 4; mt++)
    Lv[mt] = *(const vf4*)&envL[(size_t)(b0 + c) * 64 + 16 * mt + 4 * g];

  for (int oi = 0; oi < 32; oi++) {
    const int o = wave * 32 + oi;
    const unsigned short* cb = Cf + (size_t)(o * 8) * 64 * 8;
    vf4 acc[4];
#pragma unroll
    for (int mt = 0; mt < 4; mt++) {
      const short8 a0 = __builtin_bit_cast(short8,
          *(const ushort8*)&cb[(size_t)((mt * 2 + 0) * 64 + lane) * 8]);
      const short8 a1 = __builtin_bit_cast(short8,
          *(const ushort8*)&cb[(size_t)((mt * 2 + 1) * 64 + lane) * 8]);
      vf4 z = {0.f, 0.f, 0.f, 0.f};
      z = __builtin_amdgcn_mfma_f32_16x16x32_bf16(a0, rf[0], z, 0, 0, 0);
      z = __builtin_amdgcn_mfma_f32_16x16x32_bf16(a1, rf[1], z, 0, 0, 0);
      acc[mt] = z;
    }
    // step 2: contract l with L (per-lane 16 terms, then g-group reduce)
    float ps = 0.f;
#pragma unroll
    for (int mt = 0; mt < 4; mt++)
#pragma unroll
      for (int r = 0; r < 4; r++) ps += Lv[mt][r] * acc[mt][r];
    ps += __shfl_xor(ps, 16);
    ps += __shfl_xor(ps, 32);
    if (g == 0) Pp[(size_t)(b0 + c) * 128 + o] = ps;
  }
}

// ---- row-normalize Pp -> out ----
__global__ __launch_bounds__(256) void combinek2(const float* __restrict__ P,
                                                 float* __restrict__ out) {
  const int row = blockIdx.x * 8 + (threadIdx.x >> 5);
  const int o0 = (threadIdx.x & 31) * 4;
  vf4 v = *(const vf4*)&P[(size_t)row * 128 + o0];
  float ss = v[0] * v[0] + v[1] * v[1] + v[2] * v[2] + v[3] * v[3];
#pragma unroll
  for (int m = 1; m < 32; m <<= 1) ss += __shfl_xor(ss, m);
  const float inv = 1.f / fmaxf(sqrtf(ss), 1e-12f);
  v *= inv;
  *(vf4*)&out[(size_t)row * 128 + o0] = v;
}

extern "C" void kernel_launch(void* const* d_in, const int* in_sizes, int n_in,
                              void* d_out, int out_size, void* d_ws, size_t ws_size,
                              hipStream_t stream) {
  const float* x = (const float*)d_in[0];
  const float* left0 = (const float*)d_in[1];
  const float* left_rest = (const float*)d_in[2];
  const float* center = (const float*)d_in[3];
  const float* right_rest = (const float*)d_in[4];
  const float* right_last = (const float*)d_in[5];
  float* out = (float*)d_out;

  char* wsb = (char*)d_ws;
  unsigned short* Wl = (unsigned short*)wsb;                         // 8.37 MB
  unsigned short* Wr = Wl + (size_t)NS * SITE_F;                     // 8.37 MB
  float* envL = (float*)(Wr + (size_t)NS * SITE_F);                  // 1 MB
  float* envR = envL + (size_t)BBATCH * 64;                          // 1 MB
  unsigned short* Lb16 = (unsigned short*)(envR + (size_t)BBATCH * 64);  // 0.5 MB
  unsigned short* Rb16 = Lb16 + (size_t)BBATCH * 64;                 // 0.5 MB
  unsigned short* Cf = Rb16 + (size_t)BBATCH * 64;                   // 1 MB
  float* Pp = (float*)(Cf + (size_t)OO * 8 * 64 * 8);                // 2 MB

  hipLaunchKernelGGL(prep, dim3(NS, 2), dim3(256), 0, stream,
                     left_rest, right_rest, Wl, Wr);
  hipLaunchKernelGGL(prep2, dim3(OO), dim3(256), 0, stream, center, Cf);
  hipLaunchKernelGGL(sweep, dim3(256), dim3(128), 0, stream,
                     x, left0, right_last, Wl, Wr, envL, envR, Lb16, Rb16);
  hipLaunchKernelGGL(centerk2, dim3(BBATCH / 16), dim3(256), 0, stream,
                     envL, Rb16, Cf, Pp);
  hipLaunchKernelGGL(combinek2, dim3(BBATCH / 8), dim3(256), 0, stream, Pp, out);
}